// Round 1
// baseline (495.558 us; speedup 1.0000x reference)
//
#include <hip/hip_runtime.h>

// RNNDecoderP round 9: collapse 4 waves -> 2 waves (1 wave/SIMD).
// wave A: L1 recurrence + gx2 = Wih2*h1 folded in (reuses the freshly
//         gathered h1a registers, lagged one step; h1 ring deleted).
// wave B: L2 recurrence + MLP head folded in (reuses gathered h2a, lagged)
//         + y drain (chunk c-2).
// Per CU: 2 blocks x 2 waves = 4 waves = 1/SIMD -> no issue arbitration on
// the serial chain. Off-chain gx2/MLP FMAs fill the trans-chain bubbles.
// Pipeline depth C+4 -> C+2.

typedef float v2f __attribute__((ext_vector_type(2)));

constexpr int Bn  = 256;
constexpr int Tn  = 2048;
constexpr int Dn  = 64;
constexpr int DBn = 32;
constexpr int Ln  = 2;
constexpr int Gn  = 96;
constexpr int Kc  = 32;     // steps per chunk/phase

#if __has_builtin(__builtin_amdgcn_exp2f)
__device__ __forceinline__ float exp2_fast(float x) { return __builtin_amdgcn_exp2f(x); }
#else
__device__ __forceinline__ float exp2_fast(float x) { return exp2f(x); }
#endif
#if __has_builtin(__builtin_amdgcn_rcpf)
__device__ __forceinline__ float rcp_fast(float x) { return __builtin_amdgcn_rcpf(x); }
#else
__device__ __forceinline__ float rcp_fast(float x) { return 1.0f / x; }
#endif

__device__ __forceinline__ float sigmoid_f(float x) {
  return rcp_fast(1.0f + exp2_fast(-1.4426950408889634f * x));
}
__device__ __forceinline__ float tanh_f(float x) {
  return 1.0f - 2.0f * rcp_fast(1.0f + exp2_fast(2.8853900817779268f * x));
}

template <int CTRL>
__device__ __forceinline__ float dpp_add(float x) {
  int y = __builtin_amdgcn_update_dpp(0, __builtin_bit_cast(int, x), CTRL, 0xf, 0xf, true);
  return x + __builtin_bit_cast(float, y);
}
// cross-half (L^8) combine: row_ror:8
__device__ __forceinline__ float dppx8_add(float x) { return dpp_add<0x128>(x); }
// full 16-lane row sum, result in ALL lanes: ror8+ror4+ror2+ror1 circulant reduce
__device__ __forceinline__ float dpp_row_sum16(float x) {
  x = dpp_add<0x128>(x);
  x = dpp_add<0x124>(x);
  x = dpp_add<0x122>(x);
  x = dpp_add<0x121>(x);
  return x;
}

// 16-float half-dot, single chain (off-chain work)
__device__ __forceinline__ float dot8(const v2f* __restrict__ w, const v2f* __restrict__ h) {
  v2f a = {0.0f, 0.0f};
  #pragma unroll
  for (int q = 0; q < 8; ++q) a = __builtin_elementwise_fma(w[q], h[q], a);
  return a.x + a.y;
}
// 16-float half-dot, two chains (on-chain work)
__device__ __forceinline__ float dot8b(const v2f* __restrict__ w, const v2f* __restrict__ h) {
  v2f a = {0.0f, 0.0f}, b = {0.0f, 0.0f};
  #pragma unroll
  for (int q = 0; q < 4; ++q) {
    a = __builtin_elementwise_fma(w[q], h[q], a);
    b = __builtin_elementwise_fma(w[q + 4], h[q + 4], b);
  }
  a = a + b;
  return a.x + a.y;
}

// load 16 consecutive floats (4 x float4) into v2f[8]
__device__ __forceinline__ void ld16(const float* p, v2f* d) {
  #pragma unroll
  for (int q = 0; q < 4; ++q) {
    float4 a = ((const float4*)p)[q];
    d[2*q] = (v2f){a.x, a.y}; d[2*q+1] = (v2f){a.z, a.w};
  }
}

__global__ __launch_bounds__(128, 1)
void rnn_decoder(const int* __restrict__ band_ids, const float* __restrict__ dtime,
                 const float* __restrict__ z_last, const float* __restrict__ projW,
                 const float* __restrict__ projB, const float* __restrict__ Wih,
                 const float* __restrict__ Whh, const float* __restrict__ bih,
                 const float* __restrict__ bhh, const float* __restrict__ mW1,
                 const float* __restrict__ mb1, const float* __restrict__ mW2,
                 const float* __restrict__ mb2, float* __restrict__ out) {
  const int b    = blockIdx.x >> 1;
  const int kb   = blockIdx.x & 1;
  const int tid  = threadIdx.x;              // 0..127
  const int w    = tid >> 6;                 // wave role: 0 = L1+gx2, 1 = L2+MLP+drain
  const int L    = tid & 63;
  const int e    = (L & 7) | ((L >> 4) << 3);// owned element/gate 0..31
  const int koff = ((L >> 3) & 1) * 16;      // K-half (bit 3 -> DPP partner L^8)

  __shared__ __align__(16) float yd[Tn];               // compacted dtime -> y
  __shared__ __align__(16) float gxr_[2][Kc][DBn][4];  // A -> B packed gx2 gates
  __shared__ __align__(16) float vr_[2][Kc][4];        // B MLP -> B drain partials
  __shared__ __align__(16) float h1b[DBn];             // A self-gather buffer
  __shared__ __align__(16) float h2b[DBn];             // B self-gather buffer
  __shared__ __align__(16) float xb[DBn], xs[DBn];
  __shared__ int nsh;

  const float mb2v = mb2[kb];

  if (w == 0) {
    // ======== setup: compaction, proj fold, affine consts, Whh1 + Wih2 slices ====
    {
      const int*   brow = band_ids + b * Tn;
      const float* drow = dtime    + b * Tn;
      int cnt = 0;
      int4 bcache[8];
      #pragma unroll
      for (int it = 0; it < 8; ++it) {
        int4 v = ((const int4*)(brow + L * 32))[it];
        bcache[it] = v;
        cnt += (v.x == kb) + (v.y == kb) + (v.z == kb) + (v.w == kb);
      }
      int incl = cnt;
      #pragma unroll
      for (int dlt = 1; dlt < 64; dlt <<= 1) {
        int v = __shfl_up(incl, dlt, 64);
        if (L >= dlt) incl += v;
      }
      int off = incl - cnt;
      const int n0 = __shfl(incl, 63, 64);
      #pragma unroll
      for (int it = 0; it < 8; ++it) {
        int4   v  = bcache[it];
        float4 dd = ((const float4*)(drow + L * 32))[it];
        if (v.x == kb) yd[off++] = dd.x;
        if (v.y == kb) yd[off++] = dd.y;
        if (v.z == kb) yd[off++] = dd.z;
        if (v.w == kb) yd[off++] = dd.w;
      }
      if (L == 0) nsh = n0;
    }
    {
      const float* pw = projW + (kb * (Dn + 1)) * DBn + e;
      const float* zl = z_last + b * Dn;
      float acc = 0.0f;
      #pragma unroll 8
      for (int k = 0; k < Dn; ++k) acc = fmaf(zl[k], pw[k * DBn], acc);
      xb[e] = acc + projB[kb * DBn + e];   // partner lanes write identical values
      xs[e] = pw[Dn * DBn];
    }
    __builtin_amdgcn_wave_barrier();
    const float* wih1  = Wih + ((kb * Ln + 0) * Gn) * DBn;
    const float* bih1p = bih + (kb * Ln + 0) * Gn;
    const float* bhh1p = bhh + (kb * Ln + 0) * Gn;
    float gb_r = 0, gb_z = 0, gb_n = 0, gs_r = 0, gs_z = 0, gs_n = 0;
    #pragma unroll 4
    for (int j = 0; j < DBn; ++j) {
      float xbv = xb[j], xsv = xs[j];
      float wr = wih1[(     e) * DBn + j];
      float wz = wih1[(32 + e) * DBn + j];
      float wn = wih1[(64 + e) * DBn + j];
      gb_r = fmaf(wr, xbv, gb_r);  gs_r = fmaf(wr, xsv, gs_r);
      gb_z = fmaf(wz, xbv, gb_z);  gs_z = fmaf(wz, xsv, gs_z);
      gb_n = fmaf(wn, xbv, gb_n);  gs_n = fmaf(wn, xsv, gs_n);
    }
    gb_r += bih1p[e]      + bhh1p[e];
    gb_z += bih1p[32 + e] + bhh1p[32 + e];
    gb_n += bih1p[64 + e];
    const float bhh1n = bhh1p[64 + e];
    v2f w1r[8], w1z[8], w1n[8];
    const float* whh1 = Whh + ((kb * Ln + 0) * Gn) * DBn;
    ld16(whh1 + (     e) * DBn + koff, w1r);
    ld16(whh1 + (32 + e) * DBn + koff, w1z);
    ld16(whh1 + (64 + e) * DBn + koff, w1n);
    // Wih2 half-rows for the folded gx2 stage
    v2f wa[8], wbv[8], wcv[8];
    const float* wih2 = Wih + ((kb * Ln + 1) * Gn) * DBn;
    ld16(wih2 + (     e) * DBn + koff, wa);
    ld16(wih2 + (32 + e) * DBn + koff, wbv);
    ld16(wih2 + (64 + e) * DBn + koff, wcv);
    __syncthreads();   // barrier A

    const int n = nsh;
    const int C = (n + Kc - 1) >> 5;
    v2f h1a[8];
    #pragma unroll
    for (int q = 0; q < 8; ++q) h1a[q] = (v2f){0.0f, 0.0f};
    float h1self = 0.0f;
    for (int c = 0; c < C + 2; ++c) {
      if (c < C) {
        float* gxc = &gxr_[c & 1][0][0][0];
        const int t0 = c * Kc;
        for (int k = 0; k < Kc; ++k) {
          float d  = yd[t0 + k];
          // ---- chain: recurrence dots on h1(t-1) ----
          float ar = dot8b(w1r, h1a);
          float az = dot8b(w1z, h1a);
          float an = dot8b(w1n, h1a);
          // ---- off-chain: gx2 for step t-1 (h1a still holds h1(t-1)) ----
          // k==0 writes a dummy into slot 0, overwritten at k==1 (branchless,
          // keeps the whole step one scheduling region so gx2 fills bubbles)
          float g0 = dot8(wa,  h1a);
          float g1 = dot8(wbv, h1a);
          float g2 = dot8(wcv, h1a);
          g0 = dppx8_add(g0);
          g1 = dppx8_add(g1);
          g2 = dppx8_add(g2);
          const int kw = k - (k > 0);
          float4 gv; gv.x = g0; gv.y = g1; gv.z = g2; gv.w = 0.0f;
          *(float4*)&gxc[(kw * DBn + e) * 4] = gv;   // 2-way same-addr write (free)
          // ---- chain continues: combine + gates ----
          ar = dppx8_add(ar);
          az = dppx8_add(az);
          an = dppx8_add(an);
          float r1 = sigmoid_f(fmaf(d, gs_r, gb_r) + ar);
          float z1 = sigmoid_f(fmaf(d, gs_z, gb_z) + az);
          float n1 = tanh_f(fmaf(d, gs_n, gb_n) + r1 * (an + bhh1n));
          h1self = fmaf(z1, h1self - n1, n1);
          h1b[e] = h1self;
          __builtin_amdgcn_wave_barrier();
          ld16(&h1b[koff], h1a);   // the only dependent DS stage
        }
        // flush gx2 for the chunk's last step (h1a = h1(t0+Kc-1))
        {
          float g0 = dot8(wa,  h1a);
          float g1 = dot8(wbv, h1a);
          float g2 = dot8(wcv, h1a);
          g0 = dppx8_add(g0);
          g1 = dppx8_add(g1);
          g2 = dppx8_add(g2);
          float4 gv; gv.x = g0; gv.y = g1; gv.z = g2; gv.w = 0.0f;
          *(float4*)&gxc[((Kc - 1) * DBn + e) * 4] = gv;
        }
      }
      __syncthreads();
    }
  } else {
    // ======== setup: Whh2 half-rows + bias consts + MLP params ========
    const float* whh2  = Whh + ((kb * Ln + 1) * Gn) * DBn;
    const float* bih2p = bih + (kb * Ln + 1) * Gn;
    const float* bhh2p = bhh + (kb * Ln + 1) * Gn;
    v2f r2w[8], z2w[8], n2w[8];
    ld16(whh2 + (     e) * DBn + koff, r2w);
    ld16(whh2 + (32 + e) * DBn + koff, z2w);
    ld16(whh2 + (64 + e) * DBn + koff, n2w);
    const float c2r   = bih2p[e]      + bhh2p[e];
    const float c2z   = bih2p[32 + e] + bhh2p[32 + e];
    const float bih2n = bih2p[64 + e];
    const float bhh2n = bhh2p[64 + e];
    // mW1 half-column, mb1, mW2 (pre-scaled 0.5 for dual-count across lane pairs)
    v2f m1c[8];
    #pragma unroll
    for (int q = 0; q < 8; ++q)
      m1c[q] = (v2f){ mW1[(kb * DBn + koff + 2*q)     * DBn + e],
                      mW1[(kb * DBn + koff + 2*q + 1) * DBn + e] };
    const float mb1e = mb1[kb * DBn + e];
    const float mW2h = 0.5f * mW2[kb * DBn + e];
    // n==0 fallback partials (only consumed when C==0)
    {
      float p = fmaxf(mb1e, 0.0f) * mW2h;
      p = dpp_row_sum16(p);
      if ((L & 15) == 15) vr_[0][0][L >> 4] = p;
    }
    __syncthreads();   // barrier A

    const int n = nsh;
    const int C = (n + Kc - 1) >> 5;
    v2f h2a[8];
    #pragma unroll
    for (int q = 0; q < 8; ++q) h2a[q] = (v2f){0.0f, 0.0f};
    float h2self = 0.0f;
    for (int c = 0; c < C + 2; ++c) {
      if (c >= 1 && c <= C) {
        const int cc = c - 1;
        const float* gxc = &gxr_[cc & 1][0][0][0];
        float* vrc = &vr_[cc & 1][0][0];
        for (int k = 0; k < Kc; ++k) {
          float4 g = *(const float4*)&gxc[(k * DBn + e) * 4];  // one b128, pre-produced
          // ---- chain: recurrence dots on h2(t-1) ----
          float cr = dot8b(r2w, h2a);
          float cz = dot8b(z2w, h2a);
          float cn = dot8b(n2w, h2a);
          // ---- off-chain: MLP head for step t-1 (h2a still holds h2(t-1)) ----
          float mh = dot8(m1c, h2a);
          mh = dppx8_add(mh);
          float v = fmaxf(mh + mb1e, 0.0f) * mW2h;
          v = dpp_row_sum16(v);                    // pure-VALU 16-lane reduce
          const int kw = k - (k > 0);
          if ((L & 15) == 15) vrc[kw * 4 + (L >> 4)] = v;
          // ---- chain continues ----
          cr = dppx8_add(cr);
          cz = dppx8_add(cz);
          cn = dppx8_add(cn);
          float r2v = sigmoid_f(g.x + cr + c2r);
          float z2v = sigmoid_f(g.y + cz + c2z);
          float n2v = tanh_f(g.z + bih2n + r2v * (cn + bhh2n));
          h2self = fmaf(z2v, h2self - n2v, n2v);
          h2b[e] = h2self;
          __builtin_amdgcn_wave_barrier();
          ld16(&h2b[koff], h2a);   // chain ends here
        }
        // flush MLP for the chunk's last step
        {
          float mh = dot8(m1c, h2a);
          mh = dppx8_add(mh);
          float v = fmaxf(mh + mb1e, 0.0f) * mW2h;
          v = dpp_row_sum16(v);
          if ((L & 15) == 15) vrc[(Kc - 1) * 4 + (L >> 4)] = v;
        }
      }
      if (c >= 2 && L < 32) {
        const int cd = c - 2;                      // drain y for chunk cd
        float4 p = *(const float4*)&vr_[cd & 1][L][0];
        yd[cd * Kc + L] = ((p.x + p.y) + (p.z + p.w)) + mb2v;
      }
      __syncthreads();
    }
  }

  // ================= joint epilogue =================
  const int nf = nsh;
  float ylast;
  if (nf > 0) {
    ylast = yd[nf - 1];
  } else {
    float4 p = *(const float4*)&vr_[0][0][0];
    ylast = ((p.x + p.y) + (p.z + p.w)) + mb2v;
  }
  for (int t = nf + tid; t < Tn; t += 128) yd[t] = ylast;
  __syncthreads();

  float* orow = out + (kb * Bn + b) * Tn;
  for (int q = tid; q < Tn / 4; q += 128)
    ((float4*)orow)[q] = ((const float4*)yd)[q];
}

extern "C" void kernel_launch(void* const* d_in, const int* in_sizes, int n_in,
                              void* d_out, int out_size, void* d_ws, size_t ws_size,
                              hipStream_t stream) {
  const int*   band_ids = (const int*)  d_in[0];
  const float* dtime    = (const float*)d_in[1];
  const float* z_last   = (const float*)d_in[2];
  const float* projW    = (const float*)d_in[3];
  const float* projB    = (const float*)d_in[4];
  const float* Wih      = (const float*)d_in[5];
  const float* Whh      = (const float*)d_in[6];
  const float* bihp     = (const float*)d_in[7];
  const float* bhhp     = (const float*)d_in[8];
  const float* mW1      = (const float*)d_in[9];
  const float* mb1      = (const float*)d_in[10];
  const float* mW2      = (const float*)d_in[11];
  const float* mb2      = (const float*)d_in[12];
  float* out = (float*)d_out;
  rnn_decoder<<<dim3(Bn * 2), dim3(128), 0, stream>>>(
      band_ids, dtime, z_last, projW, projB, Wih, Whh, bihp, bhhp,
      mW1, mb1, mW2, mb2, out);
}

// Round 2
// 376.962 us; speedup vs baseline: 1.3146x; 1.3146x over previous
//
#include <hip/hip_runtime.h>

// RNNDecoderP round 10: 2 chains per 256-thread block, 1 wave/SIMD, folded roles.
// w0: L1+gx2 chain0   w1: L1+gx2 chain1   w2: L2+MLP+drain chain0   w3: ... chain1
// Chains b and b+128 share kb -> identical weights in the paired waves.
// amdgpu_waves_per_eu(1,1) pins regalloc to 1 wave/EU (512 VGPR budget) so the
// 6 resident v2f[8] weight arrays stay in registers (round-9's remat killer).
// Kc=16 so per-chain gxr rings fit LDS (~51.5 KB). Pipeline depth C+2.

typedef float v2f __attribute__((ext_vector_type(2)));

constexpr int Bn  = 256;
constexpr int Tn  = 2048;
constexpr int Dn  = 64;
constexpr int DBn = 32;
constexpr int Ln  = 2;
constexpr int Gn  = 96;
constexpr int Kc  = 16;     // steps per chunk/phase

#if __has_builtin(__builtin_amdgcn_exp2f)
__device__ __forceinline__ float exp2_fast(float x) { return __builtin_amdgcn_exp2f(x); }
#else
__device__ __forceinline__ float exp2_fast(float x) { return exp2f(x); }
#endif
#if __has_builtin(__builtin_amdgcn_rcpf)
__device__ __forceinline__ float rcp_fast(float x) { return __builtin_amdgcn_rcpf(x); }
#else
__device__ __forceinline__ float rcp_fast(float x) { return 1.0f / x; }
#endif

__device__ __forceinline__ float sigmoid_f(float x) {
  return rcp_fast(1.0f + exp2_fast(-1.4426950408889634f * x));
}
__device__ __forceinline__ float tanh_f(float x) {
  return 1.0f - 2.0f * rcp_fast(1.0f + exp2_fast(2.8853900817779268f * x));
}

template <int CTRL>
__device__ __forceinline__ float dpp_add(float x) {
  int y = __builtin_amdgcn_update_dpp(0, __builtin_bit_cast(int, x), CTRL, 0xf, 0xf, true);
  return x + __builtin_bit_cast(float, y);
}
// cross-half (L^8) combine: row_ror:8
__device__ __forceinline__ float dppx8_add(float x) { return dpp_add<0x128>(x); }
// full 16-lane row sum, result in ALL lanes: ror8+ror4+ror2+ror1 circulant reduce
__device__ __forceinline__ float dpp_row_sum16(float x) {
  x = dpp_add<0x128>(x);
  x = dpp_add<0x124>(x);
  x = dpp_add<0x122>(x);
  x = dpp_add<0x121>(x);
  return x;
}

// 16-float half-dot, single chain (off-chain work)
__device__ __forceinline__ float dot8(const v2f* __restrict__ w, const v2f* __restrict__ h) {
  v2f a = {0.0f, 0.0f};
  #pragma unroll
  for (int q = 0; q < 8; ++q) a = __builtin_elementwise_fma(w[q], h[q], a);
  return a.x + a.y;
}
// 16-float half-dot, two chains (on-chain work)
__device__ __forceinline__ float dot8b(const v2f* __restrict__ w, const v2f* __restrict__ h) {
  v2f a = {0.0f, 0.0f}, b = {0.0f, 0.0f};
  #pragma unroll
  for (int q = 0; q < 4; ++q) {
    a = __builtin_elementwise_fma(w[q], h[q], a);
    b = __builtin_elementwise_fma(w[q + 4], h[q + 4], b);
  }
  a = a + b;
  return a.x + a.y;
}

// load 16 consecutive floats (4 x float4) into v2f[8]
__device__ __forceinline__ void ld16(const float* p, v2f* d) {
  #pragma unroll
  for (int q = 0; q < 4; ++q) {
    float4 a = ((const float4*)p)[q];
    d[2*q] = (v2f){a.x, a.y}; d[2*q+1] = (v2f){a.z, a.w};
  }
}

__global__ __launch_bounds__(256)
__attribute__((amdgpu_waves_per_eu(1, 1)))
void rnn_decoder(const int* __restrict__ band_ids, const float* __restrict__ dtime,
                 const float* __restrict__ z_last, const float* __restrict__ projW,
                 const float* __restrict__ projB, const float* __restrict__ Wih,
                 const float* __restrict__ Whh, const float* __restrict__ bih,
                 const float* __restrict__ bhh, const float* __restrict__ mW1,
                 const float* __restrict__ mb1, const float* __restrict__ mW2,
                 const float* __restrict__ mb2, float* __restrict__ out) {
  const int bpair = blockIdx.x >> 1;         // 0..127
  const int kb    = blockIdx.x & 1;
  const int tid   = threadIdx.x;             // 0..255
  const int w     = tid >> 6;                // wave id
  const int chain = w & 1;                   // which of the two chains
  const int role  = w >> 1;                  // 0 = L1+gx2, 1 = L2+MLP+drain
  const int b     = bpair + (chain << 7);    // batch row for this chain
  const int L     = tid & 63;
  const int e     = (L & 7) | ((L >> 4) << 3); // owned element/gate 0..31
  const int koff  = ((L >> 3) & 1) * 16;       // K-half (bit 3 -> DPP partner L^8)

  __shared__ __align__(16) float yd[2][Tn];                 // per-chain dtime -> y (16 KB)
  __shared__ __align__(16) float gxr_[2][2][Kc][DBn][4];    // per-chain gx2 rings (32 KB)
  __shared__ __align__(16) float vr_[2][2][Kc][4];          // per-chain MLP partials (2 KB)
  __shared__ __align__(16) float hb_[2][2][DBn];            // per-chain per-role gather buf
  __shared__ __align__(16) float xb[2][DBn], xs[2][DBn];
  __shared__ int nsh[2];

  const float mb2v = mb2[kb];
  float* ydc = &yd[chain][0];

  if (role == 0) {
    // ======== setup: compaction, proj fold, affine consts, Whh1 + Wih2 slices ====
    {
      const int*   brow = band_ids + b * Tn;
      const float* drow = dtime    + b * Tn;
      int cnt = 0;
      int4 bcache[8];
      #pragma unroll
      for (int it = 0; it < 8; ++it) {
        int4 v = ((const int4*)(brow + L * 32))[it];
        bcache[it] = v;
        cnt += (v.x == kb) + (v.y == kb) + (v.z == kb) + (v.w == kb);
      }
      int incl = cnt;
      #pragma unroll
      for (int dlt = 1; dlt < 64; dlt <<= 1) {
        int v = __shfl_up(incl, dlt, 64);
        if (L >= dlt) incl += v;
      }
      int off = incl - cnt;
      const int n0 = __shfl(incl, 63, 64);
      #pragma unroll
      for (int it = 0; it < 8; ++it) {
        int4   v  = bcache[it];
        float4 dd = ((const float4*)(drow + L * 32))[it];
        if (v.x == kb) ydc[off++] = dd.x;
        if (v.y == kb) ydc[off++] = dd.y;
        if (v.z == kb) ydc[off++] = dd.z;
        if (v.w == kb) ydc[off++] = dd.w;
      }
      if (L == 0) nsh[chain] = n0;
    }
    {
      const float* pw = projW + (kb * (Dn + 1)) * DBn + e;
      const float* zl = z_last + b * Dn;
      float acc = 0.0f;
      #pragma unroll 8
      for (int k = 0; k < Dn; ++k) acc = fmaf(zl[k], pw[k * DBn], acc);
      xb[chain][e] = acc + projB[kb * DBn + e];   // partner lanes write identical values
      xs[chain][e] = pw[Dn * DBn];
    }
    __builtin_amdgcn_wave_barrier();
    const float* wih1  = Wih + ((kb * Ln + 0) * Gn) * DBn;
    const float* bih1p = bih + (kb * Ln + 0) * Gn;
    const float* bhh1p = bhh + (kb * Ln + 0) * Gn;
    float gb_r = 0, gb_z = 0, gb_n = 0, gs_r = 0, gs_z = 0, gs_n = 0;
    #pragma unroll 4
    for (int j = 0; j < DBn; ++j) {
      float xbv = xb[chain][j], xsv = xs[chain][j];
      float wr = wih1[(     e) * DBn + j];
      float wz = wih1[(32 + e) * DBn + j];
      float wn = wih1[(64 + e) * DBn + j];
      gb_r = fmaf(wr, xbv, gb_r);  gs_r = fmaf(wr, xsv, gs_r);
      gb_z = fmaf(wz, xbv, gb_z);  gs_z = fmaf(wz, xsv, gs_z);
      gb_n = fmaf(wn, xbv, gb_n);  gs_n = fmaf(wn, xsv, gs_n);
    }
    gb_r += bih1p[e]      + bhh1p[e];
    gb_z += bih1p[32 + e] + bhh1p[32 + e];
    gb_n += bih1p[64 + e];
    const float bhh1n = bhh1p[64 + e];
    v2f w1r[8], w1z[8], w1n[8];
    const float* whh1 = Whh + ((kb * Ln + 0) * Gn) * DBn;
    ld16(whh1 + (     e) * DBn + koff, w1r);
    ld16(whh1 + (32 + e) * DBn + koff, w1z);
    ld16(whh1 + (64 + e) * DBn + koff, w1n);
    // Wih2 half-rows for the folded gx2 stage
    v2f wa[8], wbv[8], wcv[8];
    const float* wih2 = Wih + ((kb * Ln + 1) * Gn) * DBn;
    ld16(wih2 + (     e) * DBn + koff, wa);
    ld16(wih2 + (32 + e) * DBn + koff, wbv);
    ld16(wih2 + (64 + e) * DBn + koff, wcv);
    __syncthreads();   // barrier A

    const int C  = (nsh[chain] + Kc - 1) >> 4;
    const int Co = (nsh[chain ^ 1] + Kc - 1) >> 4;
    const int CM = (C > Co ? C : Co);
    float* hbc = &hb_[chain][0][0];
    v2f h1a[8];
    #pragma unroll
    for (int q = 0; q < 8; ++q) h1a[q] = (v2f){0.0f, 0.0f};
    float h1self = 0.0f;
    for (int c = 0; c < CM + 2; ++c) {
      if (c < C) {
        float* gxc = &gxr_[chain][c & 1][0][0][0];
        const int t0 = c * Kc;
        for (int k = 0; k < Kc; ++k) {
          float d  = ydc[t0 + k];
          // ---- chain: recurrence dots on h1(t-1) ----
          float ar = dot8b(w1r, h1a);
          float az = dot8b(w1z, h1a);
          float an = dot8b(w1n, h1a);
          // ---- off-chain: gx2 for step t-1 (h1a still holds h1(t-1)) ----
          float g0 = dot8(wa,  h1a);
          float g1 = dot8(wbv, h1a);
          float g2 = dot8(wcv, h1a);
          g0 = dppx8_add(g0);
          g1 = dppx8_add(g1);
          g2 = dppx8_add(g2);
          const int kw = k - (k > 0);   // dummy slot at k==0, overwritten at k==1
          float4 gv; gv.x = g0; gv.y = g1; gv.z = g2; gv.w = 0.0f;
          *(float4*)&gxc[(kw * DBn + e) * 4] = gv;   // 2-way same-addr write (free)
          // ---- chain continues: combine + gates ----
          ar = dppx8_add(ar);
          az = dppx8_add(az);
          an = dppx8_add(an);
          float r1 = sigmoid_f(fmaf(d, gs_r, gb_r) + ar);
          float z1 = sigmoid_f(fmaf(d, gs_z, gb_z) + az);
          float n1 = tanh_f(fmaf(d, gs_n, gb_n) + r1 * (an + bhh1n));
          h1self = fmaf(z1, h1self - n1, n1);
          hbc[e] = h1self;
          __builtin_amdgcn_wave_barrier();
          ld16(&hbc[koff], h1a);   // the only dependent DS stage
        }
        // flush gx2 for the chunk's last step (h1a = h1(t0+Kc-1))
        {
          float g0 = dot8(wa,  h1a);
          float g1 = dot8(wbv, h1a);
          float g2 = dot8(wcv, h1a);
          g0 = dppx8_add(g0);
          g1 = dppx8_add(g1);
          g2 = dppx8_add(g2);
          float4 gv; gv.x = g0; gv.y = g1; gv.z = g2; gv.w = 0.0f;
          *(float4*)&gxc[((Kc - 1) * DBn + e) * 4] = gv;
        }
      }
      __syncthreads();
    }
  } else {
    // ======== setup: Whh2 half-rows + bias consts + MLP params ========
    const float* whh2  = Whh + ((kb * Ln + 1) * Gn) * DBn;
    const float* bih2p = bih + (kb * Ln + 1) * Gn;
    const float* bhh2p = bhh + (kb * Ln + 1) * Gn;
    v2f r2w[8], z2w[8], n2w[8];
    ld16(whh2 + (     e) * DBn + koff, r2w);
    ld16(whh2 + (32 + e) * DBn + koff, z2w);
    ld16(whh2 + (64 + e) * DBn + koff, n2w);
    const float c2r   = bih2p[e]      + bhh2p[e];
    const float c2z   = bih2p[32 + e] + bhh2p[32 + e];
    const float bih2n = bih2p[64 + e];
    const float bhh2n = bhh2p[64 + e];
    // mW1 half-column, mb1, mW2 (pre-scaled 0.5 for dual-count across lane pairs)
    v2f m1c[8];
    #pragma unroll
    for (int q = 0; q < 8; ++q)
      m1c[q] = (v2f){ mW1[(kb * DBn + koff + 2*q)     * DBn + e],
                      mW1[(kb * DBn + koff + 2*q + 1) * DBn + e] };
    const float mb1e = mb1[kb * DBn + e];
    const float mW2h = 0.5f * mW2[kb * DBn + e];
    // n==0 fallback partials (only consumed when C==0)
    {
      float p = fmaxf(mb1e, 0.0f) * mW2h;
      p = dpp_row_sum16(p);
      if ((L & 15) == 15) vr_[chain][0][0][L >> 4] = p;
    }
    __syncthreads();   // barrier A

    const int C  = (nsh[chain] + Kc - 1) >> 4;
    const int Co = (nsh[chain ^ 1] + Kc - 1) >> 4;
    const int CM = (C > Co ? C : Co);
    float* hbc = &hb_[chain][1][0];
    v2f h2a[8];
    #pragma unroll
    for (int q = 0; q < 8; ++q) h2a[q] = (v2f){0.0f, 0.0f};
    float h2self = 0.0f;
    for (int c = 0; c < CM + 2; ++c) {
      if (c >= 1 && c <= C) {
        const int cc = c - 1;
        const float* gxc = &gxr_[chain][cc & 1][0][0][0];
        float* vrc = &vr_[chain][cc & 1][0][0];
        for (int k = 0; k < Kc; ++k) {
          float4 g = *(const float4*)&gxc[(k * DBn + e) * 4];  // one b128, pre-produced
          // ---- chain: recurrence dots on h2(t-1) ----
          float cr = dot8b(r2w, h2a);
          float cz = dot8b(z2w, h2a);
          float cn = dot8b(n2w, h2a);
          // ---- off-chain: MLP head for step t-1 (h2a still holds h2(t-1)) ----
          float mh = dot8(m1c, h2a);
          mh = dppx8_add(mh);
          float v = fmaxf(mh + mb1e, 0.0f) * mW2h;
          v = dpp_row_sum16(v);                    // pure-VALU 16-lane reduce
          const int kw = k - (k > 0);
          if ((L & 15) == 15) vrc[kw * 4 + (L >> 4)] = v;
          // ---- chain continues ----
          cr = dppx8_add(cr);
          cz = dppx8_add(cz);
          cn = dppx8_add(cn);
          float r2v = sigmoid_f(g.x + cr + c2r);
          float z2v = sigmoid_f(g.y + cz + c2z);
          float n2v = tanh_f(g.z + bih2n + r2v * (cn + bhh2n));
          h2self = fmaf(z2v, h2self - n2v, n2v);
          hbc[e] = h2self;
          __builtin_amdgcn_wave_barrier();
          ld16(&hbc[koff], h2a);   // chain ends here
        }
        // flush MLP for the chunk's last step
        {
          float mh = dot8(m1c, h2a);
          mh = dppx8_add(mh);
          float v = fmaxf(mh + mb1e, 0.0f) * mW2h;
          v = dpp_row_sum16(v);
          if ((L & 15) == 15) vrc[(Kc - 1) * 4 + (L >> 4)] = v;
        }
      }
      if (c >= 2 && L < Kc) {
        const int cd = c - 2;                      // drain y for chunk cd
        if (cd < C) {
          float4 p = *(const float4*)&vr_[chain][cd & 1][L][0];
          ydc[cd * Kc + L] = ((p.x + p.y) + (p.z + p.w)) + mb2v;
        }
      }
      __syncthreads();
    }
  }

  // ================= joint epilogue (per-chain: waves {0,2} chain0, {1,3} chain1) ===
  const int nf = nsh[chain];
  const int ct = ((w >> 1) << 6) | L;              // 0..127 within this chain's pair
  float ylast;
  if (nf > 0) {
    ylast = ydc[nf - 1];
  } else {
    float4 p = *(const float4*)&vr_[chain][0][0][0];
    ylast = ((p.x + p.y) + (p.z + p.w)) + mb2v;
  }
  for (int t = nf + ct; t < Tn; t += 128) ydc[t] = ylast;
  __syncthreads();

  float* orow = out + (kb * Bn + b) * Tn;
  for (int q = ct; q < Tn / 4; q += 128)
    ((float4*)orow)[q] = ((const float4*)ydc)[q];
}

extern "C" void kernel_launch(void* const* d_in, const int* in_sizes, int n_in,
                              void* d_out, int out_size, void* d_ws, size_t ws_size,
                              hipStream_t stream) {
  const int*   band_ids = (const int*)  d_in[0];
  const float* dtime    = (const float*)d_in[1];
  const float* z_last   = (const float*)d_in[2];
  const float* projW    = (const float*)d_in[3];
  const float* projB    = (const float*)d_in[4];
  const float* Wih      = (const float*)d_in[5];
  const float* Whh      = (const float*)d_in[6];
  const float* bihp     = (const float*)d_in[7];
  const float* bhhp     = (const float*)d_in[8];
  const float* mW1      = (const float*)d_in[9];
  const float* mb1      = (const float*)d_in[10];
  const float* mW2      = (const float*)d_in[11];
  const float* mb2      = (const float*)d_in[12];
  float* out = (float*)d_out;
  rnn_decoder<<<dim3(Bn), dim3(256), 0, stream>>>(
      band_ids, dtime, z_last, projW, projB, Wih, Whh, bihp, bhhp,
      mW1, mb1, mW2, mb2, out);
}

// Round 3
// 375.752 us; speedup vs baseline: 1.3188x; 1.0032x over previous
//
#include <hip/hip_runtime.h>

// RNNDecoderP round 11: round-8 4-wave pipeline + two surgical chain cuts.
// (1) Self-gather via ds_bpermute (register crossbar): kills the per-step
//     ds_write -> wave_barrier -> ld16 -> lgkmcnt round-trip (~130 cyc) on
//     both recurrence chains. Ring writes remain (consumed by w1/w3 only).
// (2) Kc 32 -> 16: pipeline skew overhead halves (4 chunks = 64 step-slots).
// Roles unchanged: w0 L1 rec, w1 gx2+y-drain, w2 L2 rec, w3 MLP head.

typedef float v2f __attribute__((ext_vector_type(2)));

constexpr int Bn  = 256;
constexpr int Tn  = 2048;
constexpr int Dn  = 64;
constexpr int DBn = 32;
constexpr int Ln  = 2;
constexpr int Gn  = 96;
constexpr int Kc  = 16;     // steps per chunk/phase

#if __has_builtin(__builtin_amdgcn_exp2f)
__device__ __forceinline__ float exp2_fast(float x) { return __builtin_amdgcn_exp2f(x); }
#else
__device__ __forceinline__ float exp2_fast(float x) { return exp2f(x); }
#endif
#if __has_builtin(__builtin_amdgcn_rcpf)
__device__ __forceinline__ float rcp_fast(float x) { return __builtin_amdgcn_rcpf(x); }
#else
__device__ __forceinline__ float rcp_fast(float x) { return 1.0f / x; }
#endif

__device__ __forceinline__ float sigmoid_f(float x) {
  return rcp_fast(1.0f + exp2_fast(-1.4426950408889634f * x));
}
__device__ __forceinline__ float tanh_f(float x) {
  return 1.0f - 2.0f * rcp_fast(1.0f + exp2_fast(2.8853900817779268f * x));
}

template <int CTRL>
__device__ __forceinline__ float dpp_add(float x) {
  int y = __builtin_amdgcn_update_dpp(0, __builtin_bit_cast(int, x), CTRL, 0xf, 0xf, true);
  return x + __builtin_bit_cast(float, y);
}
// cross-half (L^8) combine: row_ror:8
__device__ __forceinline__ float dppx8_add(float x) { return dpp_add<0x128>(x); }
// full 16-lane row sum, result in ALL lanes: ror8+ror4+ror2+ror1 circulant reduce
__device__ __forceinline__ float dpp_row_sum16(float x) {
  x = dpp_add<0x128>(x);
  x = dpp_add<0x124>(x);
  x = dpp_add<0x122>(x);
  x = dpp_add<0x121>(x);
  return x;
}

// 16-float half-dot, single chain (off-chain work)
__device__ __forceinline__ float dot8(const v2f* __restrict__ w, const v2f* __restrict__ h) {
  v2f a = {0.0f, 0.0f};
  #pragma unroll
  for (int q = 0; q < 8; ++q) a = __builtin_elementwise_fma(w[q], h[q], a);
  return a.x + a.y;
}
// 16-float half-dot, two chains (on-chain work)
__device__ __forceinline__ float dot8b(const v2f* __restrict__ w, const v2f* __restrict__ h) {
  v2f a = {0.0f, 0.0f}, b = {0.0f, 0.0f};
  #pragma unroll
  for (int q = 0; q < 4; ++q) {
    a = __builtin_elementwise_fma(w[q], h[q], a);
    b = __builtin_elementwise_fma(w[q + 4], h[q + 4], b);
  }
  a = a + b;
  return a.x + a.y;
}

// load 16 consecutive floats (4 x float4) into v2f[8]
__device__ __forceinline__ void ld16(const float* p, v2f* d) {
  #pragma unroll
  for (int q = 0; q < 4; ++q) {
    float4 a = ((const float4*)p)[q];
    d[2*q] = (v2f){a.x, a.y}; d[2*q+1] = (v2f){a.z, a.w};
  }
}

// self-gather of the 16 owned-half h values via ds_bpermute (register crossbar).
// Element j lives in lane 16*(j>>3)+(j&7); lane needs j = koff+m, m=0..15.
// byte addr = 128*bit3(L) + 64*(m>>3) + 4*(m&7)  -> uniform base + const offset.
__device__ __forceinline__ void bperm_gather16(int addr0, float hval, v2f* d) {
  const int hb = __builtin_bit_cast(int, hval);
  #pragma unroll
  for (int q = 0; q < 8; ++q) {
    const int m0 = 2 * q, m1 = 2 * q + 1;
    int lo = __builtin_amdgcn_ds_bpermute(addr0 + 64 * (m0 >> 3) + 4 * (m0 & 7), hb);
    int hi = __builtin_amdgcn_ds_bpermute(addr0 + 64 * (m1 >> 3) + 4 * (m1 & 7), hb);
    d[q] = (v2f){ __builtin_bit_cast(float, lo), __builtin_bit_cast(float, hi) };
  }
}

__global__ __launch_bounds__(256, 1)
void rnn_decoder(const int* __restrict__ band_ids, const float* __restrict__ dtime,
                 const float* __restrict__ z_last, const float* __restrict__ projW,
                 const float* __restrict__ projB, const float* __restrict__ Wih,
                 const float* __restrict__ Whh, const float* __restrict__ bih,
                 const float* __restrict__ bhh, const float* __restrict__ mW1,
                 const float* __restrict__ mb1, const float* __restrict__ mW2,
                 const float* __restrict__ mb2, float* __restrict__ out) {
  const int b    = blockIdx.x >> 1;
  const int kb   = blockIdx.x & 1;
  const int tid  = threadIdx.x;              // 0..255
  const int w    = tid >> 6;                 // wave role
  const int L    = tid & 63;
  const int e    = (L & 7) | ((L >> 4) << 3);// owned element/gate 0..31
  const int koff = ((L >> 3) & 1) * 16;      // K-half (bit 3 -> DPP partner L^8)
  const int addr0 = (L & 8) << 4;            // bpermute base: 128*bit3(L)

  __shared__ __align__(16) float yd[Tn];               // compacted dtime -> y
  __shared__ __align__(16) float gxr_[2][Kc][DBn][4];  // w1 -> w2 packed gates
  __shared__ __align__(16) float h1r_[2][Kc][DBn];     // w0 -> w1 ring
  __shared__ __align__(16) float h2r_[2][Kc][DBn];     // w2 -> w3 ring
  __shared__ __align__(16) float vr_[2][Kc][4];        // w3 -> w1 y-partials
  __shared__ __align__(16) float xb[DBn], xs[DBn];
  __shared__ int nsh;

  const float mb2v = mb2[kb];

  if (w == 0) {
    // ======== setup: compaction, proj fold, affine consts, Whh1 slices ========
    {
      const int*   brow = band_ids + b * Tn;
      const float* drow = dtime    + b * Tn;
      int cnt = 0;
      int4 bcache[8];
      #pragma unroll
      for (int it = 0; it < 8; ++it) {
        int4 v = ((const int4*)(brow + L * 32))[it];
        bcache[it] = v;
        cnt += (v.x == kb) + (v.y == kb) + (v.z == kb) + (v.w == kb);
      }
      int incl = cnt;
      #pragma unroll
      for (int dlt = 1; dlt < 64; dlt <<= 1) {
        int v = __shfl_up(incl, dlt, 64);
        if (L >= dlt) incl += v;
      }
      int off = incl - cnt;
      const int n0 = __shfl(incl, 63, 64);
      #pragma unroll
      for (int it = 0; it < 8; ++it) {
        int4   v  = bcache[it];
        float4 dd = ((const float4*)(drow + L * 32))[it];
        if (v.x == kb) yd[off++] = dd.x;
        if (v.y == kb) yd[off++] = dd.y;
        if (v.z == kb) yd[off++] = dd.z;
        if (v.w == kb) yd[off++] = dd.w;
      }
      if (L == 0) nsh = n0;
    }
    {
      const float* pw = projW + (kb * (Dn + 1)) * DBn + e;
      const float* zl = z_last + b * Dn;
      float acc = 0.0f;
      #pragma unroll 8
      for (int k = 0; k < Dn; ++k) acc = fmaf(zl[k], pw[k * DBn], acc);
      xb[e] = acc + projB[kb * DBn + e];   // partner lanes write identical values
      xs[e] = pw[Dn * DBn];
    }
    __builtin_amdgcn_wave_barrier();
    const float* wih1  = Wih + ((kb * Ln + 0) * Gn) * DBn;
    const float* bih1p = bih + (kb * Ln + 0) * Gn;
    const float* bhh1p = bhh + (kb * Ln + 0) * Gn;
    float gb_r = 0, gb_z = 0, gb_n = 0, gs_r = 0, gs_z = 0, gs_n = 0;
    #pragma unroll 4
    for (int j = 0; j < DBn; ++j) {
      float xbv = xb[j], xsv = xs[j];
      float wr = wih1[(     e) * DBn + j];
      float wz = wih1[(32 + e) * DBn + j];
      float wn = wih1[(64 + e) * DBn + j];
      gb_r = fmaf(wr, xbv, gb_r);  gs_r = fmaf(wr, xsv, gs_r);
      gb_z = fmaf(wz, xbv, gb_z);  gs_z = fmaf(wz, xsv, gs_z);
      gb_n = fmaf(wn, xbv, gb_n);  gs_n = fmaf(wn, xsv, gs_n);
    }
    gb_r += bih1p[e]      + bhh1p[e];
    gb_z += bih1p[32 + e] + bhh1p[32 + e];
    gb_n += bih1p[64 + e];
    const float bhh1n = bhh1p[64 + e];
    v2f w1r[8], w1z[8], w1n[8];
    const float* whh1 = Whh + ((kb * Ln + 0) * Gn) * DBn;
    ld16(whh1 + (     e) * DBn + koff, w1r);
    ld16(whh1 + (32 + e) * DBn + koff, w1z);
    ld16(whh1 + (64 + e) * DBn + koff, w1n);
    __syncthreads();   // barrier A

#if __has_builtin(__builtin_amdgcn_s_setprio)
    __builtin_amdgcn_s_setprio(1);   // recurrence wave: win issue arbitration
#endif
    const int n = nsh;
    const int C = (n + Kc - 1) >> 4;
    v2f h1a[8];
    #pragma unroll
    for (int q = 0; q < 8; ++q) h1a[q] = (v2f){0.0f, 0.0f};
    float h1self = 0.0f;
    for (int c = 0; c < C + 4; ++c) {
      if (c < C) {
        float* ring = &h1r_[c & 1][0][0];
        const int t0 = c * Kc;
        for (int k = 0; k < Kc; ++k) {
          float d  = yd[t0 + k];
          float ar = dot8b(w1r, h1a);
          float az = dot8b(w1z, h1a);
          float an = dot8b(w1n, h1a);
          ar = dppx8_add(ar);
          az = dppx8_add(az);
          an = dppx8_add(an);
          float r1 = sigmoid_f(fmaf(d, gs_r, gb_r) + ar);
          float z1 = sigmoid_f(fmaf(d, gs_z, gb_z) + az);
          float n1 = tanh_f(fmaf(d, gs_n, gb_n) + r1 * (an + bhh1n));
          h1self = fmaf(z1, h1self - n1, n1);
          // self-gather via register crossbar (no LDS round-trip on the chain)
          bperm_gather16(addr0, h1self, h1a);
          ring[k * DBn + e] = h1self;     // publish for w1 (fire-and-forget)
        }
      }
      __syncthreads();
    }
  } else if (w == 1) {
    // ======== setup: Wih2 half-rows ========
    const float* wih2 = Wih + ((kb * Ln + 1) * Gn) * DBn;
    v2f wa[8], wbv[8], wcv[8];
    ld16(wih2 + (     e) * DBn + koff, wa);
    ld16(wih2 + (32 + e) * DBn + koff, wbv);
    ld16(wih2 + (64 + e) * DBn + koff, wcv);
    __syncthreads();   // barrier A

    const int n = nsh;
    const int C = (n + Kc - 1) >> 4;
    for (int c = 0; c < C + 4; ++c) {
      if (c >= 1 && c <= C) {
        const int cp = c - 1;
        const float* hsrc = &h1r_[cp & 1][0][0];
        for (int k = 0; k < Kc; ++k) {
          v2f hb[8];
          ld16(&hsrc[k * DBn + koff], hb);
          float g0 = dot8(wa,  hb);
          float g1 = dot8(wbv, hb);
          float g2 = dot8(wcv, hb);
          g0 = dppx8_add(g0);
          g1 = dppx8_add(g1);
          g2 = dppx8_add(g2);
          float4 gv; gv.x = g0; gv.y = g1; gv.z = g2; gv.w = 0.0f;
          *(float4*)&gxr_[cp & 1][k][e][0] = gv;   // 2-way same-addr write (free)
        }
      }
      if (c >= 4) {
        const int cd = c - 4;                      // drain y for chunk cd
        if (cd < C && L < Kc) {
          float4 p = *(const float4*)&vr_[cd & 1][L][0];
          yd[cd * Kc + L] = ((p.x + p.y) + (p.z + p.w)) + mb2v;
        }
      }
      __syncthreads();
    }
  } else if (w == 2) {
    // ======== setup: Whh2 half-rows + bias consts ========
    const float* whh2  = Whh + ((kb * Ln + 1) * Gn) * DBn;
    const float* bih2p = bih + (kb * Ln + 1) * Gn;
    const float* bhh2p = bhh + (kb * Ln + 1) * Gn;
    v2f r2w[8], z2w[8], n2w[8];
    ld16(whh2 + (     e) * DBn + koff, r2w);
    ld16(whh2 + (32 + e) * DBn + koff, z2w);
    ld16(whh2 + (64 + e) * DBn + koff, n2w);
    const float c2r   = bih2p[e]      + bhh2p[e];
    const float c2z   = bih2p[32 + e] + bhh2p[32 + e];
    const float bih2n = bih2p[64 + e];
    const float bhh2n = bhh2p[64 + e];
    __syncthreads();   // barrier A

#if __has_builtin(__builtin_amdgcn_s_setprio)
    __builtin_amdgcn_s_setprio(1);   // recurrence wave
#endif
    const int n = nsh;
    const int C = (n + Kc - 1) >> 4;
    v2f h2a[8];
    #pragma unroll
    for (int q = 0; q < 8; ++q) h2a[q] = (v2f){0.0f, 0.0f};
    float h2self = 0.0f;
    for (int c = 0; c < C + 4; ++c) {
      if (c >= 2 && c <= C + 1) {
        const int cc = c - 2;
        float* ring = &h2r_[cc & 1][0][0];
        for (int k = 0; k < Kc; ++k) {
          float4 g = *(const float4*)&gxr_[cc & 1][k][e][0];  // one b128, pre-produced
          float cr = dot8b(r2w, h2a);
          float cz = dot8b(z2w, h2a);
          float cn = dot8b(n2w, h2a);
          cr = dppx8_add(cr);
          cz = dppx8_add(cz);
          cn = dppx8_add(cn);
          float r2v = sigmoid_f(g.x + cr + c2r);
          float z2v = sigmoid_f(g.y + cz + c2z);
          float n2v = tanh_f(g.z + bih2n + r2v * (cn + bhh2n));
          h2self = fmaf(z2v, h2self - n2v, n2v);
          // self-gather via register crossbar (no LDS round-trip on the chain)
          bperm_gather16(addr0, h2self, h2a);
          ring[k * DBn + e] = h2self;     // publish for w3 (fire-and-forget)
        }
      }
      __syncthreads();
    }
  } else {
    // ======== setup: mW1 half-column, mb1, mW2 (pre-scaled 0.5 for dual-count) ====
    v2f m1c[8];
    #pragma unroll
    for (int q = 0; q < 8; ++q)
      m1c[q] = (v2f){ mW1[(kb * DBn + koff + 2*q)     * DBn + e],
                      mW1[(kb * DBn + koff + 2*q + 1) * DBn + e] };
    const float mb1e = mb1[kb * DBn + e];
    const float mW2h = 0.5f * mW2[kb * DBn + e];
    // n==0 fallback partials (only consumed when C==0)
    {
      float p = fmaxf(mb1e, 0.0f) * mW2h;
      p = dpp_row_sum16(p);
      if ((L & 15) == 15) vr_[0][0][L >> 4] = p;
    }
    __syncthreads();   // barrier A

    const int n = nsh;
    const int C = (n + Kc - 1) >> 4;
    for (int c = 0; c < C + 4; ++c) {
      if (c >= 3 && c <= C + 2) {
        const int cm = c - 3;
        const float* hsrc = &h2r_[cm & 1][0][0];
        for (int k = 0; k < Kc; ++k) {
          v2f hb[8];
          ld16(&hsrc[k * DBn + koff], hb);
          float mh = dot8(m1c, hb);
          mh = dppx8_add(mh);
          float v = fmaxf(mh + mb1e, 0.0f) * mW2h;
          v = dpp_row_sum16(v);                    // pure-VALU 16-lane reduce
          if ((L & 15) == 15) vr_[cm & 1][k][L >> 4] = v;
        }
      }
      __syncthreads();
    }
  }

  // ================= joint epilogue =================
  const int n = nsh;
  float ylast;
  if (n > 0) {
    ylast = yd[n - 1];
  } else {
    float4 p = *(const float4*)&vr_[0][0][0];
    ylast = ((p.x + p.y) + (p.z + p.w)) + mb2v;
  }
  for (int t = n + tid; t < Tn; t += 256) yd[t] = ylast;
  __syncthreads();

  float* orow = out + (kb * Bn + b) * Tn;
  for (int q = tid; q < Tn / 4; q += 256)
    ((float4*)orow)[q] = ((const float4*)yd)[q];
}

extern "C" void kernel_launch(void* const* d_in, const int* in_sizes, int n_in,
                              void* d_out, int out_size, void* d_ws, size_t ws_size,
                              hipStream_t stream) {
  const int*   band_ids = (const int*)  d_in[0];
  const float* dtime    = (const float*)d_in[1];
  const float* z_last   = (const float*)d_in[2];
  const float* projW    = (const float*)d_in[3];
  const float* projB    = (const float*)d_in[4];
  const float* Wih      = (const float*)d_in[5];
  const float* Whh      = (const float*)d_in[6];
  const float* bihp     = (const float*)d_in[7];
  const float* bhhp     = (const float*)d_in[8];
  const float* mW1      = (const float*)d_in[9];
  const float* mb1      = (const float*)d_in[10];
  const float* mW2      = (const float*)d_in[11];
  const float* mb2      = (const float*)d_in[12];
  float* out = (float*)d_out;
  rnn_decoder<<<dim3(Bn * 2), dim3(256), 0, stream>>>(
      band_ids, dtime, z_last, projW, projB, Wih, Whh, bihp, bhhp,
      mW1, mb1, mW2, mb2, out);
}

// Round 5
// 372.319 us; speedup vs baseline: 1.3310x; 1.0092x over previous
//
#include <hip/hip_runtime.h>

// RNNDecoderP round 12 (resubmit; round-4 bench was an infra timeout):
// round-8 4-wave pipeline + SIMD role complementarity.
// (1) REVERT bpermute (33.8M bank conflicts + VGPR collapse). Back to
//     ds_write -> wave_barrier -> ld16 self-gather (proven 291us path).
// (2) role = w ^ bit8(blockIdx): co-resident blocks (b, b+256 under the
//     %8 XCD round-robin) get complementary wave->SIMD role maps, so each
//     SIMD hosts ONE recurrence wave + ONE cheap helper instead of two
//     recurrence waves. Helper instrs fill the recurrence stalls.
// (3) Kc 32 -> 16: pipeline skew overhead halves (64 step-slots).
// Roles: L1 rec | gx2 + y-drain | L2 rec | MLP head.

typedef float v2f __attribute__((ext_vector_type(2)));

constexpr int Bn  = 256;
constexpr int Tn  = 2048;
constexpr int Dn  = 64;
constexpr int DBn = 32;
constexpr int Ln  = 2;
constexpr int Gn  = 96;
constexpr int Kc  = 16;     // steps per chunk/phase

#if __has_builtin(__builtin_amdgcn_exp2f)
__device__ __forceinline__ float exp2_fast(float x) { return __builtin_amdgcn_exp2f(x); }
#else
__device__ __forceinline__ float exp2_fast(float x) { return exp2f(x); }
#endif
#if __has_builtin(__builtin_amdgcn_rcpf)
__device__ __forceinline__ float rcp_fast(float x) { return __builtin_amdgcn_rcpf(x); }
#else
__device__ __forceinline__ float rcp_fast(float x) { return 1.0f / x; }
#endif

__device__ __forceinline__ float sigmoid_f(float x) {
  return rcp_fast(1.0f + exp2_fast(-1.4426950408889634f * x));
}
__device__ __forceinline__ float tanh_f(float x) {
  return 1.0f - 2.0f * rcp_fast(1.0f + exp2_fast(2.8853900817779268f * x));
}

template <int CTRL>
__device__ __forceinline__ float dpp_add(float x) {
  int y = __builtin_amdgcn_update_dpp(0, __builtin_bit_cast(int, x), CTRL, 0xf, 0xf, true);
  return x + __builtin_bit_cast(float, y);
}
// cross-half (L^8) combine: row_ror:8
__device__ __forceinline__ float dppx8_add(float x) { return dpp_add<0x128>(x); }
// full 16-lane row sum, result in ALL lanes: ror8+ror4+ror2+ror1 circulant reduce
__device__ __forceinline__ float dpp_row_sum16(float x) {
  x = dpp_add<0x128>(x);
  x = dpp_add<0x124>(x);
  x = dpp_add<0x122>(x);
  x = dpp_add<0x121>(x);
  return x;
}

// 16-float half-dot, single chain (off-chain work)
__device__ __forceinline__ float dot8(const v2f* __restrict__ w, const v2f* __restrict__ h) {
  v2f a = {0.0f, 0.0f};
  #pragma unroll
  for (int q = 0; q < 8; ++q) a = __builtin_elementwise_fma(w[q], h[q], a);
  return a.x + a.y;
}
// 16-float half-dot, two chains (on-chain work)
__device__ __forceinline__ float dot8b(const v2f* __restrict__ w, const v2f* __restrict__ h) {
  v2f a = {0.0f, 0.0f}, b = {0.0f, 0.0f};
  #pragma unroll
  for (int q = 0; q < 4; ++q) {
    a = __builtin_elementwise_fma(w[q], h[q], a);
    b = __builtin_elementwise_fma(w[q + 4], h[q + 4], b);
  }
  a = a + b;
  return a.x + a.y;
}

// load 16 consecutive floats (4 x float4) into v2f[8]
__device__ __forceinline__ void ld16(const float* p, v2f* d) {
  #pragma unroll
  for (int q = 0; q < 4; ++q) {
    float4 a = ((const float4*)p)[q];
    d[2*q] = (v2f){a.x, a.y}; d[2*q+1] = (v2f){a.z, a.w};
  }
}

__global__ __launch_bounds__(256, 1)
void rnn_decoder(const int* __restrict__ band_ids, const float* __restrict__ dtime,
                 const float* __restrict__ z_last, const float* __restrict__ projW,
                 const float* __restrict__ projB, const float* __restrict__ Wih,
                 const float* __restrict__ Whh, const float* __restrict__ bih,
                 const float* __restrict__ bhh, const float* __restrict__ mW1,
                 const float* __restrict__ mb1, const float* __restrict__ mW2,
                 const float* __restrict__ mb2, float* __restrict__ out) {
  const int b    = blockIdx.x >> 1;
  const int kb   = blockIdx.x & 1;
  const int tid  = threadIdx.x;              // 0..255
  const int wv   = tid >> 6;                 // physical wave (SIMD slot)
  // Complementary role map between co-resident blocks (b and b+256 under the
  // %8 XCD round-robin): each SIMD gets one recurrence wave + one helper.
  const int w    = wv ^ ((blockIdx.x >> 8) & 1);
  const int L    = tid & 63;
  const int e    = (L & 7) | ((L >> 4) << 3);// owned element/gate 0..31
  const int koff = ((L >> 3) & 1) * 16;      // K-half (bit 3 -> DPP partner L^8)

  __shared__ __align__(16) float yd[Tn];               // compacted dtime -> y
  __shared__ __align__(16) float gxr_[2][Kc][DBn][4];  // gx2 -> L2 packed gates
  __shared__ __align__(16) float h1r_[2][Kc][DBn];     // L1 -> gx2 ring
  __shared__ __align__(16) float h2r_[2][Kc][DBn];     // L2 -> MLP ring (+ own readback)
  __shared__ __align__(16) float vr_[2][Kc][4];        // MLP -> drain y-partials
  __shared__ __align__(16) float xb[DBn], xs[DBn];
  __shared__ int nsh;

  const float mb2v = mb2[kb];

  if (w == 0) {
    // ======== setup: compaction, proj fold, affine consts, Whh1 slices ========
    {
      const int*   brow = band_ids + b * Tn;
      const float* drow = dtime    + b * Tn;
      int cnt = 0;
      int4 bcache[8];
      #pragma unroll
      for (int it = 0; it < 8; ++it) {
        int4 v = ((const int4*)(brow + L * 32))[it];
        bcache[it] = v;
        cnt += (v.x == kb) + (v.y == kb) + (v.z == kb) + (v.w == kb);
      }
      int incl = cnt;
      #pragma unroll
      for (int dlt = 1; dlt < 64; dlt <<= 1) {
        int v = __shfl_up(incl, dlt, 64);
        if (L >= dlt) incl += v;
      }
      int off = incl - cnt;
      const int n0 = __shfl(incl, 63, 64);
      #pragma unroll
      for (int it = 0; it < 8; ++it) {
        int4   v  = bcache[it];
        float4 dd = ((const float4*)(drow + L * 32))[it];
        if (v.x == kb) yd[off++] = dd.x;
        if (v.y == kb) yd[off++] = dd.y;
        if (v.z == kb) yd[off++] = dd.z;
        if (v.w == kb) yd[off++] = dd.w;
      }
      if (L == 0) nsh = n0;
    }
    {
      const float* pw = projW + (kb * (Dn + 1)) * DBn + e;
      const float* zl = z_last + b * Dn;
      float acc = 0.0f;
      #pragma unroll 8
      for (int k = 0; k < Dn; ++k) acc = fmaf(zl[k], pw[k * DBn], acc);
      xb[e] = acc + projB[kb * DBn + e];   // partner lanes write identical values
      xs[e] = pw[Dn * DBn];
    }
    __builtin_amdgcn_wave_barrier();
    const float* wih1  = Wih + ((kb * Ln + 0) * Gn) * DBn;
    const float* bih1p = bih + (kb * Ln + 0) * Gn;
    const float* bhh1p = bhh + (kb * Ln + 0) * Gn;
    float gb_r = 0, gb_z = 0, gb_n = 0, gs_r = 0, gs_z = 0, gs_n = 0;
    #pragma unroll 4
    for (int j = 0; j < DBn; ++j) {
      float xbv = xb[j], xsv = xs[j];
      float wr = wih1[(     e) * DBn + j];
      float wz = wih1[(32 + e) * DBn + j];
      float wn = wih1[(64 + e) * DBn + j];
      gb_r = fmaf(wr, xbv, gb_r);  gs_r = fmaf(wr, xsv, gs_r);
      gb_z = fmaf(wz, xbv, gb_z);  gs_z = fmaf(wz, xsv, gs_z);
      gb_n = fmaf(wn, xbv, gb_n);  gs_n = fmaf(wn, xsv, gs_n);
    }
    gb_r += bih1p[e]      + bhh1p[e];
    gb_z += bih1p[32 + e] + bhh1p[32 + e];
    gb_n += bih1p[64 + e];
    const float bhh1n = bhh1p[64 + e];
    v2f w1r[8], w1z[8], w1n[8];
    const float* whh1 = Whh + ((kb * Ln + 0) * Gn) * DBn;
    ld16(whh1 + (     e) * DBn + koff, w1r);
    ld16(whh1 + (32 + e) * DBn + koff, w1z);
    ld16(whh1 + (64 + e) * DBn + koff, w1n);
    __syncthreads();   // barrier A

#if __has_builtin(__builtin_amdgcn_s_setprio)
    __builtin_amdgcn_s_setprio(1);   // recurrence wave: win issue arbitration
#endif
    const int n = nsh;
    const int C = (n + Kc - 1) >> 4;
    v2f h1a[8];
    #pragma unroll
    for (int q = 0; q < 8; ++q) h1a[q] = (v2f){0.0f, 0.0f};
    float h1self = 0.0f;
    for (int c = 0; c < C + 4; ++c) {
      if (c < C) {
        float* ring = &h1r_[c & 1][0][0];
        const int t0 = c * Kc;
        for (int k = 0; k < Kc; ++k) {
          float d  = yd[t0 + k];
          float ar = dot8b(w1r, h1a);
          float az = dot8b(w1z, h1a);
          float an = dot8b(w1n, h1a);
          ar = dppx8_add(ar);
          az = dppx8_add(az);
          an = dppx8_add(an);
          float r1 = sigmoid_f(fmaf(d, gs_r, gb_r) + ar);
          float z1 = sigmoid_f(fmaf(d, gs_z, gb_z) + az);
          float n1 = tanh_f(fmaf(d, gs_n, gb_n) + r1 * (an + bhh1n));
          h1self = fmaf(z1, h1self - n1, n1);
          ring[k * DBn + e] = h1self;
          __builtin_amdgcn_wave_barrier();
          ld16(&ring[k * DBn + koff], h1a);   // the only dependent DS stage
        }
      }
      __syncthreads();
    }
  } else if (w == 1) {
    // ======== setup: Wih2 half-rows ========
    const float* wih2 = Wih + ((kb * Ln + 1) * Gn) * DBn;
    v2f wa[8], wbv[8], wcv[8];
    ld16(wih2 + (     e) * DBn + koff, wa);
    ld16(wih2 + (32 + e) * DBn + koff, wbv);
    ld16(wih2 + (64 + e) * DBn + koff, wcv);
    __syncthreads();   // barrier A

    const int n = nsh;
    const int C = (n + Kc - 1) >> 4;
    for (int c = 0; c < C + 4; ++c) {
      if (c >= 1 && c <= C) {
        const int cp = c - 1;
        const float* hsrc = &h1r_[cp & 1][0][0];
        for (int k = 0; k < Kc; ++k) {
          v2f hb[8];
          ld16(&hsrc[k * DBn + koff], hb);
          float g0 = dot8(wa,  hb);
          float g1 = dot8(wbv, hb);
          float g2 = dot8(wcv, hb);
          g0 = dppx8_add(g0);
          g1 = dppx8_add(g1);
          g2 = dppx8_add(g2);
          float4 gv; gv.x = g0; gv.y = g1; gv.z = g2; gv.w = 0.0f;
          *(float4*)&gxr_[cp & 1][k][e][0] = gv;   // 2-way same-addr write (free)
        }
      }
      if (c >= 4) {
        const int cd = c - 4;                      // drain y for chunk cd
        if (cd < C && L < Kc) {
          float4 p = *(const float4*)&vr_[cd & 1][L][0];
          yd[cd * Kc + L] = ((p.x + p.y) + (p.z + p.w)) + mb2v;
        }
      }
      __syncthreads();
    }
  } else if (w == 2) {
    // ======== setup: Whh2 half-rows + bias consts ========
    const float* whh2  = Whh + ((kb * Ln + 1) * Gn) * DBn;
    const float* bih2p = bih + (kb * Ln + 1) * Gn;
    const float* bhh2p = bhh + (kb * Ln + 1) * Gn;
    v2f r2w[8], z2w[8], n2w[8];
    ld16(whh2 + (     e) * DBn + koff, r2w);
    ld16(whh2 + (32 + e) * DBn + koff, z2w);
    ld16(whh2 + (64 + e) * DBn + koff, n2w);
    const float c2r   = bih2p[e]      + bhh2p[e];
    const float c2z   = bih2p[32 + e] + bhh2p[32 + e];
    const float bih2n = bih2p[64 + e];
    const float bhh2n = bhh2p[64 + e];
    __syncthreads();   // barrier A

#if __has_builtin(__builtin_amdgcn_s_setprio)
    __builtin_amdgcn_s_setprio(1);   // recurrence wave
#endif
    const int n = nsh;
    const int C = (n + Kc - 1) >> 4;
    v2f h2a[8];
    #pragma unroll
    for (int q = 0; q < 8; ++q) h2a[q] = (v2f){0.0f, 0.0f};
    float h2self = 0.0f;
    for (int c = 0; c < C + 4; ++c) {
      if (c >= 2 && c <= C + 1) {
        const int cc = c - 2;
        float* ring = &h2r_[cc & 1][0][0];
        for (int k = 0; k < Kc; ++k) {
          float4 g = *(const float4*)&gxr_[cc & 1][k][e][0];  // one b128, pre-produced
          float cr = dot8b(r2w, h2a);
          float cz = dot8b(z2w, h2a);
          float cn = dot8b(n2w, h2a);
          cr = dppx8_add(cr);
          cz = dppx8_add(cz);
          cn = dppx8_add(cn);
          float r2v = sigmoid_f(g.x + cr + c2r);
          float z2v = sigmoid_f(g.y + cz + c2z);
          float n2v = tanh_f(g.z + bih2n + r2v * (cn + bhh2n));
          h2self = fmaf(z2v, h2self - n2v, n2v);
          ring[k * DBn + e] = h2self;
          __builtin_amdgcn_wave_barrier();
          ld16(&ring[k * DBn + koff], h2a);   // chain ends here; no MLP tail
        }
      }
      __syncthreads();
    }
  } else {
    // ======== setup: mW1 half-column, mb1, mW2 (pre-scaled 0.5 for dual-count) ====
    v2f m1c[8];
    #pragma unroll
    for (int q = 0; q < 8; ++q)
      m1c[q] = (v2f){ mW1[(kb * DBn + koff + 2*q)     * DBn + e],
                      mW1[(kb * DBn + koff + 2*q + 1) * DBn + e] };
    const float mb1e = mb1[kb * DBn + e];
    const float mW2h = 0.5f * mW2[kb * DBn + e];
    // n==0 fallback partials (only consumed when C==0)
    {
      float p = fmaxf(mb1e, 0.0f) * mW2h;
      p = dpp_row_sum16(p);
      if ((L & 15) == 15) vr_[0][0][L >> 4] = p;
    }
    __syncthreads();   // barrier A

    const int n = nsh;
    const int C = (n + Kc - 1) >> 4;
    for (int c = 0; c < C + 4; ++c) {
      if (c >= 3 && c <= C + 2) {
        const int cm = c - 3;
        const float* hsrc = &h2r_[cm & 1][0][0];
        for (int k = 0; k < Kc; ++k) {
          v2f hb[8];
          ld16(&hsrc[k * DBn + koff], hb);
          float mh = dot8(m1c, hb);
          mh = dppx8_add(mh);
          float v = fmaxf(mh + mb1e, 0.0f) * mW2h;
          v = dpp_row_sum16(v);                    // pure-VALU 16-lane reduce
          if ((L & 15) == 15) vr_[cm & 1][k][L >> 4] = v;
        }
      }
      __syncthreads();
    }
  }

  // ================= joint epilogue =================
  const int n = nsh;
  float ylast;
  if (n > 0) {
    ylast = yd[n - 1];
  } else {
    float4 p = *(const float4*)&vr_[0][0][0];
    ylast = ((p.x + p.y) + (p.z + p.w)) + mb2v;
  }
  for (int t = n + tid; t < Tn; t += 256) yd[t] = ylast;
  __syncthreads();

  float* orow = out + (kb * Bn + b) * Tn;
  for (int q = tid; q < Tn / 4; q += 256)
    ((float4*)orow)[q] = ((const float4*)yd)[q];
}

extern "C" void kernel_launch(void* const* d_in, const int* in_sizes, int n_in,
                              void* d_out, int out_size, void* d_ws, size_t ws_size,
                              hipStream_t stream) {
  const int*   band_ids = (const int*)  d_in[0];
  const float* dtime    = (const float*)d_in[1];
  const float* z_last   = (const float*)d_in[2];
  const float* projW    = (const float*)d_in[3];
  const float* projB    = (const float*)d_in[4];
  const float* Wih      = (const float*)d_in[5];
  const float* Whh      = (const float*)d_in[6];
  const float* bihp     = (const float*)d_in[7];
  const float* bhhp     = (const float*)d_in[8];
  const float* mW1      = (const float*)d_in[9];
  const float* mb1      = (const float*)d_in[10];
  const float* mW2      = (const float*)d_in[11];
  const float* mb2      = (const float*)d_in[12];
  float* out = (float*)d_out;
  rnn_decoder<<<dim3(Bn * 2), dim3(256), 0, stream>>>(
      band_ids, dtime, z_last, projW, projB, Wih, Whh, bihp, bhhp,
      mW1, mb1, mW2, mb2, out);
}